// Round 4
// baseline (130.692 us; speedup 1.0000x reference)
//
#include <hip/hip_runtime.h>
#include <math.h>

#define BS_ 16
#define NQ_ 900
#define NC_ 91
#define NT_ 1600
#define NROWS_ (BS_ * NQ_)       // 14400
#define TILE_R 4
#define TPB 320                  // 5 waves
#define NBLK (NROWS_ / TILE_R)   // 3600 blocks
#define KITER (NT_ / TPB)        // 5 (fallback kernel)
#define PT_LD 96                 // per-row prob-table stride (floats), 16B-mult
#define PT_BLK (TILE_R * PT_LD)  // 384 floats per block
#define PT_FLOATS (NBLK * PT_BLK)
#define SOA_FLOATS (4 * NT_)     // tx,ty,tw,th
#define GPR 400                  // float4-groups per row (1600/4)
#define GPT 80                   // groups per thread-column (400/5 iters)

typedef float f32x4 __attribute__((ext_vector_type(4)));

// ===================== kernel A: tables =====================
// Wave per row: softmax -> (2 - p) stored [row][class] (pt[blk][r][96]).
// First 7 blocks additionally transpose tboxes to component-SoA so the
// sweep's 4-consecutive-target loads are 4B-lane-stride coalesced.
__global__ __launch_bounds__(256) void table_kernel(
    const float*  __restrict__ logits,   // [NROWS_, NC_]
    const float4* __restrict__ tboxes,   // [NT_] cxcywh
    float* __restrict__ pt,              // [NBLK][TILE_R][PT_LD]
    float* __restrict__ soa)             // tx[NT_], ty[NT_], tw[NT_], th[NT_]
{
    const int w    = threadIdx.x >> 6;
    const int lane = threadIdx.x & 63;
    const int row  = blockIdx.x * TILE_R + w;

    const float* lrow = logits + row * NC_;
    const float e0 = __expf(lrow[lane]);
    const float e1 = (lane < NC_ - 64) ? __expf(lrow[64 + lane]) : 0.0f;
    float s = e0 + e1;
    #pragma unroll
    for (int off = 32; off >= 1; off >>= 1)
        s += __shfl_xor(s, off, 64);
    const float inv_s = __builtin_amdgcn_rcpf(s);

    float* dst = pt + row * PT_LD;       // == pt[blk][w][.]
    dst[lane] = fmaf(-e0, inv_s, 2.0f);
    if (lane < NC_ - 64)
        dst[64 + lane] = fmaf(-e1, inv_s, 2.0f);

    if (blockIdx.x < 7) {
        const int i = blockIdx.x * 256 + threadIdx.x;
        if (i < NT_) {
            const float4 t = tboxes[i];
            soa[i]           = t.x;
            soa[NT_ + i]     = t.y;
            soa[2 * NT_ + i] = t.z;
            soa[3 * NT_ + i] = t.w;
        }
    }
}

// ===================== kernel B: float4-store sweep =====================
// Thread owns one row (rt = tid/80) and 4 consecutive targets per iter ->
// one NT dwordx4 store (1KB/wave bursts through big write-combined
// transactions). Loads: component-SoA float4 (coalesced), int4 ids
// (coalesced), p-gathers on the LDS pipe from per-row tables. Depth-1
// load pipeline; row constants fully in registers.
__device__ __forceinline__ float cost1(
    float qcx, float qcy, float qw, float qh,
    float qx0, float qy0, float qx1, float qy1, float qarea,
    float tcx, float tcy, float tw, float th, float p)
{
    const float cb = fabsf(qcx - tcx) + fabsf(qcy - tcy)
                   + fabsf(qw - tw)  + fabsf(qh - th);
    const float tx0 = fmaf(-0.5f, tw, tcx);
    const float ty0 = fmaf(-0.5f, th, tcy);
    const float tx1 = fmaf( 0.5f, tw, tcx);
    const float ty1 = fmaf( 0.5f, th, tcy);
    const float dx = fminf(qx1, tx1) - fmaxf(qx0, tx0);
    const float dy = fminf(qy1, ty1) - fmaxf(qy0, ty0);
    const float inter = fmaxf(dx, 0.0f) * fmaxf(dy, 0.0f);
    const float uni   = fmaf(tw, th, qarea) - inter;
    const float cw = (qw + tw) - dx;     // enclosing box identity
    const float ch = (qh + th) - dy;
    const float areac = cw * ch;
    // -2*inter/uni - 2*uni/areac == -2*(inter*areac + uni^2)/(uni*areac)
    const float num = fmaf(uni, uni, inter * areac);
    const float den = uni * areac;
    const float c = fmaf(5.0f, cb, p);
    return fmaf(-2.0f * num, __builtin_amdgcn_rcpf(den), c);
}

__global__ __launch_bounds__(TPB) void sweep_v4_kernel(
    const float* __restrict__ pt,        // [NBLK][TILE_R][PT_LD]
    const float* __restrict__ pboxes,    // [NROWS_, 4]
    const float* __restrict__ soa,       // tx/ty/tw/th [NT_] each
    const int*   __restrict__ tids,      // [NT_]
    f32x4*       __restrict__ out4)      // [NROWS_ * GPR]
{
    const int tid  = threadIdx.x;
    const int blk  = blockIdx.x;
    const int base = blk * TILE_R;
    const int rt   = tid / GPT;          // row-in-tile 0..3
    const int c0   = tid - rt * GPT;     // group column 0..79

    __shared__ __align__(16) float sp[PT_BLK];  // (2-p)[row][class]

    // LDS table copy first (barrier critical path)
    if (tid < PT_BLK / 4)
        reinterpret_cast<f32x4*>(sp)[tid] =
            reinterpret_cast<const f32x4*>(pt + blk * PT_BLK)[tid];

    // row constants (registers; one divergent float4 load)
    const float4 qb = *reinterpret_cast<const float4*>(pboxes + (base + rt) * 4);
    const float qcx = qb.x, qcy = qb.y, qw = qb.z, qh = qb.w;
    const float qx0 = fmaf(-0.5f, qb.z, qb.x);
    const float qy0 = fmaf(-0.5f, qb.w, qb.y);
    const float qx1 = fmaf( 0.5f, qb.z, qb.x);
    const float qy1 = fmaf( 0.5f, qb.w, qb.y);
    const float qarea = qb.z * qb.w;

    const f32x4* txp = reinterpret_cast<const f32x4*>(soa);
    const f32x4* typ = reinterpret_cast<const f32x4*>(soa + NT_);
    const f32x4* twp = reinterpret_cast<const f32x4*>(soa + 2 * NT_);
    const f32x4* thp = reinterpret_cast<const f32x4*>(soa + 3 * NT_);
    const int4*  idp = reinterpret_cast<const int4*>(tids);

    // iter-0 loads (independent of LDS; issued pre-barrier)
    f32x4 tx = txp[c0], ty = typ[c0], tw = twp[c0], th = thp[c0];
    int4  id = idp[c0];

    const float* prow = sp + rt * PT_LD;
    f32x4* outp = out4 + (base + rt) * GPR + c0;

    __syncthreads();

    #pragma unroll
    for (int k = 0; k < 5; ++k) {
        // prefetch next iter (dead in last iter; DCE'd)
        f32x4 ntx, nty, ntw, nth; int4 nid;
        if (k < 4) {
            const int jn = c0 + GPT * (k + 1);
            ntx = txp[jn]; nty = typ[jn]; ntw = twp[jn]; nth = thp[jn];
            nid = idp[jn];
        }

        // LDS-pipe gathers for the 4 targets of this row
        const float pA = prow[id.x];
        const float pB = prow[id.y];
        const float pC = prow[id.z];
        const float pD = prow[id.w];

        f32x4 c;
        c.x = cost1(qcx,qcy,qw,qh, qx0,qy0,qx1,qy1,qarea, tx.x,ty.x,tw.x,th.x, pA);
        c.y = cost1(qcx,qcy,qw,qh, qx0,qy0,qx1,qy1,qarea, tx.y,ty.y,tw.y,th.y, pB);
        c.z = cost1(qcx,qcy,qw,qh, qx0,qy0,qx1,qy1,qarea, tx.z,ty.z,tw.z,th.z, pC);
        c.w = cost1(qcx,qcy,qw,qh, qx0,qy0,qx1,qy1,qarea, tx.w,ty.w,tw.w,th.w, pD);

        __builtin_nontemporal_store(c, outp + GPT * k);

        tx = ntx; ty = nty; tw = ntw; th = nth; id = nid;
    }
}

// ===================== fallback: proven round-0 mono kernel =====================
__global__ __launch_bounds__(TPB) void matcher_cost_kernel(
    const float* __restrict__ logits,
    const float* __restrict__ pboxes,
    const float4* __restrict__ tboxes,
    const int*   __restrict__ tids,
    float* __restrict__ out)
{
    const int base = blockIdx.x * TILE_R;
    const int tid  = threadIdx.x;
    const int lane = tid & 63;
    const int wave = tid >> 6;

    __shared__ __align__(16) float sneg[NC_ * TILE_R];

    if (wave < TILE_R) {
        const float* lrow = logits + (base + wave) * NC_;
        float v0 = lrow[lane];
        float v1 = (lane < NC_ - 64) ? lrow[64 + lane] : -INFINITY;
        float m = fmaxf(v0, v1);
        #pragma unroll
        for (int off = 32; off >= 1; off >>= 1)
            m = fmaxf(m, __shfl_xor(m, off, 64));
        float e0 = __expf(v0 - m);
        float e1 = (lane < NC_ - 64) ? __expf(v1 - m) : 0.0f;
        float s = e0 + e1;
        #pragma unroll
        for (int off = 32; off >= 1; off >>= 1)
            s += __shfl_xor(s, off, 64);
        const float inv_s = __builtin_amdgcn_rcpf(s);
        sneg[lane * TILE_R + wave] = fmaf(-e0, inv_s, 2.0f);
        if (lane < NC_ - 64)
            sneg[(64 + lane) * TILE_R + wave] = fmaf(-e1, inv_s, 2.0f);
    }

    float4 tb[KITER];
    int    id[KITER];
    #pragma unroll
    for (int k = 0; k < KITER; ++k) {
        const int j = k * TPB + tid;
        tb[k] = tboxes[j];
        id[k] = tids[j];
    }

    float qcx[TILE_R], qcy[TILE_R], qw[TILE_R], qh[TILE_R];
    float qx0[TILE_R], qy0[TILE_R], qx1[TILE_R], qy1[TILE_R], qarea[TILE_R];
    #pragma unroll
    for (int r = 0; r < TILE_R; ++r) {
        const float4 qb = *reinterpret_cast<const float4*>(pboxes + (base + r) * 4);
        qcx[r] = qb.x; qcy[r] = qb.y; qw[r] = qb.z; qh[r] = qb.w;
        qx0[r] = fmaf(-0.5f, qb.z, qb.x);
        qy0[r] = fmaf(-0.5f, qb.w, qb.y);
        qx1[r] = fmaf( 0.5f, qb.z, qb.x);
        qy1[r] = fmaf( 0.5f, qb.w, qb.y);
        qarea[r] = qb.z * qb.w;
    }

    __syncthreads();

    float4 pp[KITER];
    #pragma unroll
    for (int k = 0; k < KITER; ++k)
        pp[k] = *reinterpret_cast<const float4*>(&sneg[id[k] * TILE_R]);

    #pragma unroll
    for (int k = 0; k < KITER; ++k) {
        const int j = k * TPB + tid;
        const float4 t = tb[k];
        const float tx0 = fmaf(-0.5f, t.z, t.x);
        const float ty0 = fmaf(-0.5f, t.w, t.y);
        const float tx1 = fmaf( 0.5f, t.z, t.x);
        const float ty1 = fmaf( 0.5f, t.w, t.y);
        const float tarea = t.z * t.w;
        const float p[TILE_R] = {pp[k].x, pp[k].y, pp[k].z, pp[k].w};

        #pragma unroll
        for (int r = 0; r < TILE_R; ++r) {
            const float cb = fabsf(qcx[r] - t.x) + fabsf(qcy[r] - t.y)
                           + fabsf(qw[r]  - t.z) + fabsf(qh[r]  - t.w);
            const float dx = fminf(qx1[r], tx1) - fmaxf(qx0[r], tx0);
            const float dy = fminf(qy1[r], ty1) - fmaxf(qy0[r], ty0);
            const float inter = fmaxf(dx, 0.0f) * fmaxf(dy, 0.0f);
            const float uni   = (qarea[r] + tarea) - inter;
            const float cw = (qw[r] + t.z) - dx;
            const float ch = (qh[r] + t.w) - dy;
            const float areac = cw * ch;
            float c = fmaf(5.0f, cb, p[r]);
            c = fmaf(-2.0f * inter, __builtin_amdgcn_rcpf(uni),   c);
            c = fmaf(-2.0f * uni,   __builtin_amdgcn_rcpf(areac), c);
            __builtin_nontemporal_store(c, out + (base + r) * NT_ + j);
        }
    }
}

// ===================== host launch =====================
extern "C" void kernel_launch(void* const* d_in, const int* in_sizes, int n_in,
                              void* d_out, int out_size, void* d_ws, size_t ws_size,
                              hipStream_t stream) {
    const float*  logits = (const float*)d_in[0];   // [16,900,91]
    const float*  pboxes = (const float*)d_in[1];   // [16,900,4]
    const float4* tboxes = (const float4*)d_in[2];  // [1600,4]
    const int*    tids   = (const int*)d_in[3];     // [1600]
    float* out = (float*)d_out;                     // [16,900,1600]

    const size_t need = (size_t)(PT_FLOATS + SOA_FLOATS) * sizeof(float);  // ~5.56 MB
    if (d_ws != nullptr && ws_size >= need) {
        float* pt  = (float*)d_ws;
        float* soa = pt + PT_FLOATS;
        table_kernel<<<NBLK, 256, 0, stream>>>(logits, tboxes, pt, soa);
        sweep_v4_kernel<<<NBLK, TPB, 0, stream>>>(pt, pboxes, soa, tids, (f32x4*)out);
    } else {
        matcher_cost_kernel<<<NBLK, TPB, 0, stream>>>(logits, pboxes, tboxes, tids, out);
    }
}

// Round 5
// 114.630 us; speedup vs baseline: 1.1401x; 1.1401x over previous
//
#include <hip/hip_runtime.h>
#include <math.h>

#define BS_ 16
#define NQ_ 900
#define NC_ 91
#define NT_ 1600
#define NROWS_ (BS_ * NQ_)       // 14400
#define TILE_R 4
#define TPB 320                  // 5 waves; 1600/320 = 5 uniform iterations
#define NBLK (NROWS_ / TILE_R)   // 3600 blocks
#define KITER (NT_ / TPB)        // 5
#define PT_BLK 384               // floats per block: 91 classes * 4 rows = 364, padded to 384
#define PT_FLOATS (NBLK * PT_BLK)

// ===================== kernel A: softmax -> transposed (2-p) table =====================
// One wave per row. Writes (2 - softmax(logits)) directly in the sweep's
// per-block LDS layout: pt[blk][class][row&3]. No max-subtraction: logits
// are O(few), exp() is safe in f32, halves the shuffle chain.
__global__ __launch_bounds__(256) void softmax_table_kernel(
    const float* __restrict__ logits,    // [NROWS_, NC_]
    float* __restrict__ pt)              // [NBLK][PT_BLK]
{
    const int w    = threadIdx.x >> 6;   // row-within-block = 0..3
    const int lane = threadIdx.x & 63;
    const int row  = blockIdx.x * TILE_R + w;

    const float* lrow = logits + row * NC_;
    const float e0 = __expf(lrow[lane]);
    const float e1 = (lane < NC_ - 64) ? __expf(lrow[64 + lane]) : 0.0f;
    float s = e0 + e1;
    #pragma unroll
    for (int off = 32; off >= 1; off >>= 1)
        s += __shfl_xor(s, off, 64);
    const float inv_s = __builtin_amdgcn_rcpf(s);

    float* dst = pt + blockIdx.x * PT_BLK + w;   // + class*4
    dst[lane * 4] = fmaf(-e0, inv_s, 2.0f);
    if (lane < NC_ - 64)
        dst[(64 + lane) * 4] = fmaf(-e1, inv_s, 2.0f);
}

// ===================== kernel B: sweep with LDS table copy =====================
// Identical to the round-3 best (117.3 us) EXCEPT the output stores are
// plain cached stores instead of __builtin_nontemporal_store. Single-
// variable A/B: does NT bypass of L2 write-aggregation cost us the ~30 us
// gap between the modeled ~20 us sweep and the observed ~50 us?
__global__ __launch_bounds__(TPB) void sweep_lds_kernel(
    const float* __restrict__ pt,        // [NBLK][PT_BLK]
    const float* __restrict__ pboxes,    // [NROWS_, 4] cxcywh
    const float4* __restrict__ tboxes,   // [NT_] cxcywh
    const int*   __restrict__ tids,      // [NT_]
    float* __restrict__ out)             // [NROWS_, NT_]
{
    const int base = blockIdx.x * TILE_R;
    const int tid  = threadIdx.x;

    __shared__ __align__(16) float sneg[PT_BLK];  // (2 - p)[class][row]

    // LDS table copy: 96 float4 loads, coalesced; barrier critical path.
    if (tid < PT_BLK / 4)
        reinterpret_cast<float4*>(sneg)[tid] =
            reinterpret_cast<const float4*>(pt + blockIdx.x * PT_BLK)[tid];

    // batch global prefetch of targets (registers, independent of LDS)
    float4 tb[KITER];
    int    id[KITER];
    #pragma unroll
    for (int k = 0; k < KITER; ++k) {
        const int j = k * TPB + tid;
        tb[k] = tboxes[j];
        id[k] = tids[j];
    }

    // row constants (block-uniform addresses -> scalar loads)
    float qcx[TILE_R], qcy[TILE_R], qw[TILE_R], qh[TILE_R];
    float qx0[TILE_R], qy0[TILE_R], qx1[TILE_R], qy1[TILE_R], qarea[TILE_R];
    #pragma unroll
    for (int r = 0; r < TILE_R; ++r) {
        const float4 qb = *reinterpret_cast<const float4*>(pboxes + (base + r) * 4);
        qcx[r] = qb.x; qcy[r] = qb.y; qw[r] = qb.z; qh[r] = qb.w;
        qx0[r] = fmaf(-0.5f, qb.z, qb.x);
        qy0[r] = fmaf(-0.5f, qb.w, qb.y);
        qx1[r] = fmaf( 0.5f, qb.z, qb.x);
        qy1[r] = fmaf( 0.5f, qb.w, qb.y);
        qarea[r] = qb.z * qb.w;
    }

    __syncthreads();

    // prob gathers on the LDS pipe: one b128 per k serves all 4 rows
    float4 pp[KITER];
    #pragma unroll
    for (int k = 0; k < KITER; ++k)
        pp[k] = *reinterpret_cast<const float4*>(&sneg[id[k] * 4]);

    #pragma unroll
    for (int k = 0; k < KITER; ++k) {
        const int j = k * TPB + tid;
        const float4 t = tb[k];
        const float tx0 = fmaf(-0.5f, t.z, t.x);
        const float ty0 = fmaf(-0.5f, t.w, t.y);
        const float tx1 = fmaf( 0.5f, t.z, t.x);
        const float ty1 = fmaf( 0.5f, t.w, t.y);
        const float tarea = t.z * t.w;
        const float p[TILE_R] = {pp[k].x, pp[k].y, pp[k].z, pp[k].w};

        #pragma unroll
        for (int r = 0; r < TILE_R; ++r) {
            const float cb = fabsf(qcx[r] - t.x) + fabsf(qcy[r] - t.y)
                           + fabsf(qw[r]  - t.z) + fabsf(qh[r]  - t.w);
            const float dx = fminf(qx1[r], tx1) - fmaxf(qx0[r], tx0);
            const float dy = fminf(qy1[r], ty1) - fmaxf(qy0[r], ty0);
            const float inter = fmaxf(dx, 0.0f) * fmaxf(dy, 0.0f);
            const float uni   = (qarea[r] + tarea) - inter;
            const float cw = (qw[r] + t.z) - dx;      // enclosing box identity
            const float ch = (qh[r] + t.w) - dy;
            const float areac = cw * ch;
            // -2*inter/uni - 2*uni/areac == -2*(inter*areac + uni^2)/(uni*areac)
            const float num = fmaf(uni, uni, inter * areac);
            const float den = uni * areac;
            float c = fmaf(5.0f, cb, p[r]);
            c = fmaf(-2.0f * num, __builtin_amdgcn_rcpf(den), c);
            out[(base + r) * NT_ + j] = c;            // CACHED store (the A/B)
        }
    }
}

// ===================== fallback: proven round-0 mono kernel =====================
__global__ __launch_bounds__(TPB) void matcher_cost_kernel(
    const float* __restrict__ logits,
    const float* __restrict__ pboxes,
    const float4* __restrict__ tboxes,
    const int*   __restrict__ tids,
    float* __restrict__ out)
{
    const int base = blockIdx.x * TILE_R;
    const int tid  = threadIdx.x;
    const int lane = tid & 63;
    const int wave = tid >> 6;

    __shared__ __align__(16) float sneg[NC_ * TILE_R];

    if (wave < TILE_R) {
        const float* lrow = logits + (base + wave) * NC_;
        float v0 = lrow[lane];
        float v1 = (lane < NC_ - 64) ? lrow[64 + lane] : -INFINITY;
        float m = fmaxf(v0, v1);
        #pragma unroll
        for (int off = 32; off >= 1; off >>= 1)
            m = fmaxf(m, __shfl_xor(m, off, 64));
        float e0 = __expf(v0 - m);
        float e1 = (lane < NC_ - 64) ? __expf(v1 - m) : 0.0f;
        float s = e0 + e1;
        #pragma unroll
        for (int off = 32; off >= 1; off >>= 1)
            s += __shfl_xor(s, off, 64);
        const float inv_s = __builtin_amdgcn_rcpf(s);
        sneg[lane * TILE_R + wave] = fmaf(-e0, inv_s, 2.0f);
        if (lane < NC_ - 64)
            sneg[(64 + lane) * TILE_R + wave] = fmaf(-e1, inv_s, 2.0f);
    }

    float4 tb[KITER];
    int    id[KITER];
    #pragma unroll
    for (int k = 0; k < KITER; ++k) {
        const int j = k * TPB + tid;
        tb[k] = tboxes[j];
        id[k] = tids[j];
    }

    float qcx[TILE_R], qcy[TILE_R], qw[TILE_R], qh[TILE_R];
    float qx0[TILE_R], qy0[TILE_R], qx1[TILE_R], qy1[TILE_R], qarea[TILE_R];
    #pragma unroll
    for (int r = 0; r < TILE_R; ++r) {
        const float4 qb = *reinterpret_cast<const float4*>(pboxes + (base + r) * 4);
        qcx[r] = qb.x; qcy[r] = qb.y; qw[r] = qb.z; qh[r] = qb.w;
        qx0[r] = fmaf(-0.5f, qb.z, qb.x);
        qy0[r] = fmaf(-0.5f, qb.w, qb.y);
        qx1[r] = fmaf( 0.5f, qb.z, qb.x);
        qy1[r] = fmaf( 0.5f, qb.w, qb.y);
        qarea[r] = qb.z * qb.w;
    }

    __syncthreads();

    float4 pp[KITER];
    #pragma unroll
    for (int k = 0; k < KITER; ++k)
        pp[k] = *reinterpret_cast<const float4*>(&sneg[id[k] * TILE_R]);

    #pragma unroll
    for (int k = 0; k < KITER; ++k) {
        const int j = k * TPB + tid;
        const float4 t = tb[k];
        const float tx0 = fmaf(-0.5f, t.z, t.x);
        const float ty0 = fmaf(-0.5f, t.w, t.y);
        const float tx1 = fmaf( 0.5f, t.z, t.x);
        const float ty1 = fmaf( 0.5f, t.w, t.y);
        const float tarea = t.z * t.w;
        const float p[TILE_R] = {pp[k].x, pp[k].y, pp[k].z, pp[k].w};

        #pragma unroll
        for (int r = 0; r < TILE_R; ++r) {
            const float cb = fabsf(qcx[r] - t.x) + fabsf(qcy[r] - t.y)
                           + fabsf(qw[r]  - t.z) + fabsf(qh[r]  - t.w);
            const float dx = fminf(qx1[r], tx1) - fmaxf(qx0[r], tx0);
            const float dy = fminf(qy1[r], ty1) - fmaxf(qy0[r], ty0);
            const float inter = fmaxf(dx, 0.0f) * fmaxf(dy, 0.0f);
            const float uni   = (qarea[r] + tarea) - inter;
            const float cw = (qw[r] + t.z) - dx;
            const float ch = (qh[r] + t.w) - dy;
            const float areac = cw * ch;
            float c = fmaf(5.0f, cb, p[r]);
            c = fmaf(-2.0f * inter, __builtin_amdgcn_rcpf(uni),   c);
            c = fmaf(-2.0f * uni,   __builtin_amdgcn_rcpf(areac), c);
            __builtin_nontemporal_store(c, out + (base + r) * NT_ + j);
        }
    }
}

// ===================== host launch =====================
extern "C" void kernel_launch(void* const* d_in, const int* in_sizes, int n_in,
                              void* d_out, int out_size, void* d_ws, size_t ws_size,
                              hipStream_t stream) {
    const float*  logits = (const float*)d_in[0];   // [16,900,91]
    const float*  pboxes = (const float*)d_in[1];   // [16,900,4]
    const float4* tboxes = (const float4*)d_in[2];  // [1600,4]
    const int*    tids   = (const int*)d_in[3];     // [1600]
    float* out = (float*)d_out;                     // [16,900,1600]

    const size_t need = (size_t)PT_FLOATS * sizeof(float);   // 5.53 MB
    if (d_ws != nullptr && ws_size >= need) {
        float* pt = (float*)d_ws;
        softmax_table_kernel<<<NBLK, 256, 0, stream>>>(logits, pt);
        sweep_lds_kernel<<<NBLK, TPB, 0, stream>>>(pt, pboxes, tboxes, tids, out);
    } else {
        matcher_cost_kernel<<<NBLK, TPB, 0, stream>>>(logits, pboxes, tboxes, tids, out);
    }
}